// Round 11
// baseline (893.780 us; speedup 1.0000x reference)
//
#include <hip/hip_runtime.h>

#define W 512
#define NPX (512*512)
#define NPXT (512*784)
#define NCH 48
#define NBATCH 16

// reflect-101 index mapping into [0,511]; valid for i in [-511, 1022]
__device__ __forceinline__ int refl(int i) {
    int a = i < 0 ? -i : i;
    int b = 1022 - a;
    return a < b ? a : b;
}
__device__ __forceinline__ unsigned encf(float f) {
    unsigned u = __float_as_uint(f);
    return (u & 0x80000000u) ? ~u : (u | 0x80000000u);
}
__device__ __forceinline__ float decf(unsigned e) {
    unsigned u = (e & 0x80000000u) ? (e & 0x7FFFFFFFu) : ~e;
    return __uint_as_float(u);
}
__device__ __forceinline__ unsigned long long enc64(double d) {
    unsigned long long u = (unsigned long long)__double_as_longlong(d);
    return (u & 0x8000000000000000ULL) ? ~u : (u | 0x8000000000000000ULL);
}
__device__ __forceinline__ double dec64(unsigned long long e) {
    unsigned long long u = (e & 0x8000000000000000ULL) ? (e & 0x7FFFFFFFFFFFFFFFULL) : ~e;
    return __longlong_as_double((long long)u);
}

__global__ void initK(unsigned* minenc, unsigned* maxenc, unsigned long long* rmaxenc,
                      unsigned* rowact, unsigned* colBits) {
    int t = threadIdx.x;
    if (t < NCH) { minenc[t] = 0xFFFFFFFFu; maxenc[t] = 0u; rmaxenc[t] = 0ULL; }
    for (int i = t; i < NCH*16; i += 1024) { rowact[i] = 0u; colBits[i] = 0u; }
}

// pre-shifted weights: gw[o*288 + q] = g[q - pre] for q in [pre, pre+2r], else 0.
// pre = (4 - r%4) & 3 keeps the stage window base 16B-aligned; zero front-taps
// contribute exactly +-0 to the FMA chain -> FP-identical results.
__global__ void gaussK(float* gw) {
    int o = blockIdx.x;
    const int rr[6] = {4, 8, 17, 34, 67, 134};
    int r = rr[o];
    int pre = (4 - (r & 3)) & 3;
    float sigma = 1.4f * (float)(1 << o);
    int t = threadIdx.x;   // 512
    int n = 2*r + 1;
    float wv = 0.f;
    if (t < n) { float ft = (float)(t - r) / sigma; wv = expf(-0.5f * ft * ft); }
    __shared__ float red[512];
    red[t] = wv; __syncthreads();
    for (int s = 256; s > 0; s >>= 1) { if (t < s) red[t] += red[t + s]; __syncthreads(); }
    float sum = red[0];
    float wv2 = 0.f;
    int k = t - pre;
    if (k >= 0 && k < n) { float ft = (float)(k - r) / sigma; wv2 = expf(-0.5f * ft * ft) / sum; }
    if (t < 288) gw[o*288 + t] = wv2;
}

__global__ void minmaxK(const float4* __restrict__ x4, unsigned* minenc, unsigned* maxenc) {
    int ch = blockIdx.y, chunk = blockIdx.x, t = threadIdx.x;
    size_t base = (size_t)ch*(NPX/4) + (size_t)chunk*8192;
    float mn = 3.4e38f, mx = -3.4e38f;
    for (int i = t; i < 8192; i += 256) {
        float4 v = x4[base + i];
        mn = fminf(mn, fminf(fminf(v.x, v.y), fminf(v.z, v.w)));
        mx = fmaxf(mx, fmaxf(fmaxf(v.x, v.y), fmaxf(v.z, v.w)));
    }
    for (int o = 32; o; o >>= 1) { mn = fminf(mn, __shfl_down(mn, o)); mx = fmaxf(mx, __shfl_down(mx, o)); }
    __shared__ float smn[4], smx[4];
    if ((t & 63) == 0) { smn[t >> 6] = mn; smx[t >> 6] = mx; }
    __syncthreads();
    if (t == 0) {
        for (int i = 1; i < 4; i++) { mn = fminf(mn, smn[i]); mx = fmaxf(mx, smx[i]); }
        atomicMin(&minenc[ch], encf(mn));
        atomicMax(&maxenc[ch], encf(mx));
    }
}

__global__ void scaleK(const unsigned* minenc, const unsigned* maxenc, double* gsd) {
    int t = threadIdx.x;
    if (t >= NCH) return;
    double mn = (double)decf(minenc[t]), mx = (double)decf(maxenc[t]);
    gsd[t] = 255.0 / (mx - mn + 1e-12);
}

// Harris R (fp64 direct) + Laplacian base. 32x32 tile/block, 5.2KB LDS.
__global__ __launch_bounds__(256) void lapRK(const float* __restrict__ x, const double* __restrict__ gsd,
                      float* __restrict__ lap, double* __restrict__ Rb,
                      unsigned long long* __restrict__ rmaxenc) {
    __shared__ float in[36*36];
    int ch = blockIdx.z;
    int px0 = blockIdx.x * 32, py0 = blockIdx.y * 32;
    const float* s = x + (size_t)ch*NPX;
    int t = threadIdx.x;
    for (int i = t; i < 36*36; i += 256) {
        int yy = i / 36, xx = i - yy*36;
        in[i] = s[(size_t)refl(py0 - 2 + yy)*W + refl(px0 - 2 + xx)];
    }
    __syncthreads();
    double sd = gsd[ch], s2 = sd*sd;
    int tx = t & 31, ty0 = (t >> 5) * 4;
    int gx = px0 + tx;
    int cb = gx ? tx : 1;               // local col of window base
    double m = -1e308;
    #pragma unroll
    for (int q = 0; q < 4; q++) {
        int ly = ty0 + q;
        int gy = py0 + ly;
        int rb = gy ? ly : 1;           // local row of window base
        double w[4][4];
        #pragma unroll
        for (int j = 0; j < 4; j++) {
            const float* rp = &in[(rb + j)*36 + cb];
            w[j][0] = (double)rp[0]; w[j][1] = (double)rp[1];
            w[j][2] = (double)rp[2]; w[j][3] = (double)rp[3];
        }
        double cs1[4], cs2[4], rs[4][2];
        #pragma unroll
        for (int c2 = 0; c2 < 4; c2++) {
            cs1[c2] = w[0][c2] + 2.0*w[1][c2] + w[2][c2];
            cs2[c2] = w[1][c2] + 2.0*w[2][c2] + w[3][c2];
        }
        #pragma unroll
        for (int j = 0; j < 4; j++) {
            rs[j][0] = w[j][0] + 2.0*w[j][1] + w[j][2];
            rs[j][1] = w[j][1] + 2.0*w[j][2] + w[j][3];
        }
        double Sxx = 0, Syy = 0, Sxy = 0;
        {
            double ix, iy;
            ix = cs1[2]-cs1[0]; iy = rs[2][0]-rs[0][0]; Sxx += ix*ix; Syy += iy*iy; Sxy += ix*iy;
            ix = cs1[3]-cs1[1]; iy = rs[2][1]-rs[0][1]; Sxx += ix*ix; Syy += iy*iy; Sxy += ix*iy;
            ix = cs2[2]-cs2[0]; iy = rs[3][0]-rs[1][0]; Sxx += ix*ix; Syy += iy*iy; Sxy += ix*iy;
            ix = cs2[3]-cs2[1]; iy = rs[3][1]-rs[1][1]; Sxx += ix*ix; Syy += iy*iy; Sxy += ix*iy;
        }
        Sxx *= s2; Syy *= s2; Sxy *= s2;
        double tr = Sxx + Syy;
        double R = Sxx*Syy - Sxy*Sxy - 0.04*tr*tr;
        Rb[(size_t)ch*NPX + (size_t)gy*W + gx] = R;
        const float* c = &in[(ly+2)*36 + (tx+2)];
        double l = 2.0*((double)c[-37] + (double)c[-35] + (double)c[35] + (double)c[37]) - 8.0*(double)c[0];
        lap[(size_t)ch*NPX + (size_t)gy*W + gx] = (float)(sd * l);
        m = fmax(m, R);
    }
    for (int o = 32; o; o >>= 1) m = fmax(m, __shfl_down(m, o));
    __shared__ double sred[4];
    if ((t & 63) == 0) sred[t >> 6] = m;
    __syncthreads();
    if (t == 0) {
        for (int i = 1; i < 4; i++) m = fmax(m, sred[i]);
        atomicMax(&rmaxenc[ch], enc64(m));
    }
}

// fused threshold + 3x3 dilate; writes TRANSPOSED mask maskT[ch][x][y];
// also builds row-activity and column-activity bitmaps
__global__ __launch_bounds__(256) void maskTK(const double* __restrict__ Rb,
                                              const unsigned long long* __restrict__ rmaxenc,
                                              unsigned char* __restrict__ maskT,
                                              unsigned* __restrict__ rowact,
                                              unsigned* __restrict__ colBits) {
    __shared__ int bt[34*34];
    __shared__ unsigned char vt[32][33];
    __shared__ unsigned rw, cw;
    int ch = blockIdx.z;
    int px0 = blockIdx.x*32, py0 = blockIdx.y*32;
    double thr = 0.01 * dec64(rmaxenc[ch]);
    const double* R = Rb + (size_t)ch*NPX;
    int t = threadIdx.x;
    if (t == 0) { rw = 0u; cw = 0u; }
    for (int i = t; i < 34*34; i += 256) {
        int yy = i / 34, xx = i - yy*34;
        int gy = py0 - 1 + yy, gx = px0 - 1 + xx;
        int v = 0;
        if ((unsigned)gy < 512u && (unsigned)gx < 512u) v = (R[(size_t)gy*W + gx] > thr) ? 1 : 0;
        bt[i] = v;
    }
    __syncthreads();
    int tx = t & 31, ty0 = (t >> 5) * 4;
    int colv = 0;
    #pragma unroll
    for (int q = 0; q < 4; q++) {
        int ly = ty0 + q;
        int c = (ly+1)*34 + tx + 1;
        int v = bt[c-35] | bt[c-34] | bt[c-33] | bt[c-1] | bt[c] | bt[c+1] | bt[c+33] | bt[c+34] | bt[c+35];
        vt[tx][ly] = (unsigned char)v;
        colv |= v;
        unsigned long long bal = __ballot(v != 0);
        int lane = t & 63;
        if (lane == 0 && (unsigned)bal) atomicOr(&rw, 1u << (ty0 + q));
        if (lane == 32 && (unsigned)(bal >> 32)) atomicOr(&rw, 1u << (ty0 + q));
    }
    if (colv) atomicOr(&cw, 1u << tx);
    __syncthreads();
    int xl = t >> 3, seg = t & 7;
    uchar4 u4 = make_uchar4(vt[xl][seg*4+0], vt[xl][seg*4+1], vt[xl][seg*4+2], vt[xl][seg*4+3]);
    *(uchar4*)(maskT + (size_t)ch*NPX + (size_t)(px0 + xl)*W + py0 + seg*4) = u4;
    if (t == 0) {
        if (rw) atomicOr(&rowact[ch*16 + (py0 >> 5)], rw);
        if (cw) atomicOr(&colBits[ch*16 + blockIdx.x], cw);
    }
}

// horizontal blur, TRANSPOSED + HALO'd output Tt[ch][x][784] (y-slot = 136+y,
// plus reflected halo slots). 512 thr = 8 rows x 64 lanes; 8 outputs/lane;
// 8-tap chunks; SoA-8 LDS; weights read from GLOBAL (uniform -> SGPR).
// ES element e <-> x = e-(r+pre); interior staged via float4 (base 16B-aligned
// since pre makes r+pre = 0 mod 4), edges via refl scalars.
__global__ __launch_bounds__(512, 8) void rowblurK2(const float* __restrict__ src, float* __restrict__ Tt,
                                                    const float* __restrict__ gwo, int r, int pre, int nc8,
                                                    const unsigned* __restrict__ rowact) {
    int ch = blockIdx.y;
    int row0 = blockIdx.x * 8;
    int t = threadIdx.x;
    // early exit: no masked row in [row0-r-8, row0+7+r+8]  (slop 8 covers
    // the zero-weight padded taps consumed downstream in colblur)
    {
        int lo = row0 - r - 8; if (lo < 0) lo = 0;
        int hi = row0 + 15 + r; if (hi > 511) hi = 511;   // +7 rows +8 slop
        int w0 = lo >> 5, w1 = hi >> 5;
        int lane = t & 63;
        unsigned any = 0;
        if (lane <= w1 - w0) {
            int wi = w0 + lane;
            unsigned word = rowact[ch*16 + wi];
            int b0 = wi*32;
            int lo2 = lo > b0 ? lo - b0 : 0;
            int hi2 = hi < b0 + 31 ? hi - b0 : 31;
            unsigned mlo = ~0u << lo2;
            unsigned mhi = (hi2 == 31) ? ~0u : ((1u << (hi2 + 1)) - 1u);
            any = word & mlo & mhi;
        }
        if (!__any((int)(any != 0))) return;
    }
    __shared__ float ES[8*784];
    int lr = t >> 6, xi = t & 63;
    const float* s = src + (size_t)ch*NPX + (size_t)(row0 + lr)*W;
    int rp = r + pre;                    // 0 mod 4
    int nstage = 512 + 8*nc8;
    float* ESr = ES + lr*784;
    // interior: x = 4q, element e = rp + 4q  (phases lane-constant)
    for (int q = xi; q < 128; q += 64) {
        float4 v = *(const float4*)(s + 4*q);
        int e0 = rp + 4*q;
        ESr[((e0+0)&7)*98 + ((e0+0)>>3)] = v.x;
        ESr[((e0+1)&7)*98 + ((e0+1)>>3)] = v.y;
        ESr[((e0+2)&7)*98 + ((e0+2)>>3)] = v.z;
        ESr[((e0+3)&7)*98 + ((e0+3)>>3)] = v.w;
    }
    // edges (reflected)
    for (int e = xi; e < rp; e += 64)
        ESr[(e&7)*98 + (e>>3)] = s[refl(e - rp)];
    for (int e = rp + 512 + xi; e < nstage; e += 64)
        ESr[(e&7)*98 + (e>>3)] = s[refl(e - rp)];
    float a[8];
    #pragma unroll
    for (int m = 0; m < 8; m++) a[m] = 0.f;
    for (int cc = 0; cc < nc8; ++cc) {
        float wv[8], f[15];
        #pragma unroll
        for (int i = 0; i < 8; i++) wv[i] = gwo[8*cc + i];   // uniform -> s_load
        #pragma unroll
        for (int j = 0; j < 15; j++) f[j] = ESr[(j & 7)*98 + (xi + cc + (j >> 3))];
        #pragma unroll
        for (int m = 0; m < 8; m++) {
            #pragma unroll
            for (int i = 0; i < 8; i++) a[m] = fmaf(wv[i], f[m + i], a[m]);
        }
    }
    __syncthreads();   // ES SoA dead; reuse as restage ot[512][9]
    #pragma unroll
    for (int m = 0; m < 8; m++) ES[(8*xi + m)*9 + lr] = a[m];
    __syncthreads();
    // write-out: thread t -> col t, main slot 136+y (+ reflected halos)
    {
        const float* o = ES + t*9;
        float* trow = Tt + (size_t)ch*NPXT + (size_t)t*784;
        float4* d = (float4*)(trow + 136 + row0);
        d[0] = make_float4(o[0], o[1], o[2], o[3]);
        d[1] = make_float4(o[4], o[5], o[6], o[7]);
        if (row0 <= 136 || row0 + 7 >= 375) {
            #pragma unroll
            for (int m = 0; m < 8; m++) {
                int y = row0 + m;
                if (y >= 1 && y <= 136)    trow[136 - y]  = o[m];
                if (y >= 375 && y <= 510)  trow[1158 - y] = o[m];
            }
        }
    }
}

// vertical blur as horizontal on halo'd Tt. 512 thr = 8 x-rows x 64 lanes;
// contiguous float4 staging (no refl), weights via SGPR, barrier-free
// (each wave stages/reads only its own ES row). Mask-gated FMA per wave.
template<int WRITE0>
__global__ __launch_bounds__(512, 8) void colblurK2(const float* __restrict__ Tt,
                                                    const unsigned char* __restrict__ maskT,
                                                    float* __restrict__ outT,
                                                    const float* __restrict__ gwo,
                                                    int r, int pre, int nc8, float sigma,
                                                    const unsigned* __restrict__ colBits) {
    __shared__ float ES[8*784];
    int b = blockIdx.y;
    int x0 = blockIdx.x * 8;
    int t = threadIdx.x;
    int lr = t >> 6, xi = t & 63;
    float vm[8];
    #pragma unroll
    for (int m = 0; m < 8; m++) vm[m] = 0.f;
    int anyAct = 0;
    int base = 136 - r - pre;            // 0 mod 4
    int n4 = (512 + 8*nc8) >> 2;         // float4 count (nstage mult of 4)
    float* ESr = ES + lr*784;
    for (int c = 0; c < 3; ++c) {
        int ch = b*3 + c;
        unsigned cbits = (colBits[ch*16 + (x0 >> 5)] >> (x0 & 31)) & 0xFFu;
        if (!cbits) continue;            // uniform per block
        anyAct = 1;
        const float* s = Tt + (size_t)ch*NPXT + (size_t)(x0 + lr)*784 + base;
        for (int q = xi; q < n4; q += 64) {
            float4 v = *(const float4*)(s + 4*q);
            int e0 = 4*q;                // phases lane-constant
            ESr[((e0+0)&7)*98 + ((e0+0)>>3)] = v.x;
            ESr[((e0+1)&7)*98 + ((e0+1)>>3)] = v.y;
            ESr[((e0+2)&7)*98 + ((e0+2)>>3)] = v.z;
            ESr[((e0+3)&7)*98 + ((e0+3)>>3)] = v.w;
        }
        const uchar4* mp = (const uchar4*)(maskT + (size_t)ch*NPX + (size_t)(x0 + lr)*W + 8*xi);
        uchar4 m0 = mp[0], m1 = mp[1];
        unsigned mk = 0;
        mk |=  (m0.x?1u:0u)|(m0.y?2u:0u)|(m0.z?4u:0u)|(m0.w?8u:0u);
        mk |= ((m1.x?1u:0u)|(m1.y?2u:0u)|(m1.z?4u:0u)|(m1.w?8u:0u)) << 4;
        if (__any((int)(mk != 0))) {
            float a[8];
            #pragma unroll
            for (int m = 0; m < 8; m++) a[m] = 0.f;
            for (int cc = 0; cc < nc8; ++cc) {
                float wv[8], f[15];
                #pragma unroll
                for (int i = 0; i < 8; i++) wv[i] = gwo[8*cc + i];   // uniform -> s_load
                #pragma unroll
                for (int j = 0; j < 15; j++) f[j] = ESr[(j & 7)*98 + (xi + cc + (j >> 3))];
                #pragma unroll
                for (int m = 0; m < 8; m++) {
                    #pragma unroll
                    for (int i = 0; i < 8; i++) a[m] = fmaf(wv[i], f[m + i], a[m]);
                }
            }
            #pragma unroll
            for (int m = 0; m < 8; m++)
                if (mk & (1u << m)) vm[m] = fmaxf(vm[m], sigma * fabsf(a[m]));
        }
    }
    if (!WRITE0 && !anyAct) return;
    float* ob = outT + (size_t)b*NPX + (size_t)(x0 + lr)*W + 8*xi;
    #pragma unroll
    for (int q = 0; q < 2; q++) {
        float4 vv = make_float4(vm[4*q], vm[4*q+1], vm[4*q+2], vm[4*q+3]);
        if (!WRITE0) {
            float4 cur = ((const float4*)ob)[q];
            vv.x = fmaxf(vv.x, cur.x); vv.y = fmaxf(vv.y, cur.y);
            vv.z = fmaxf(vv.z, cur.z); vv.w = fmaxf(vv.w, cur.w);
        }
        ((float4*)ob)[q] = vv;
    }
}

// final transpose: out[b][y][x] = outT[b][x][y]
__global__ __launch_bounds__(256) void transposeK(const float* __restrict__ outT, float* __restrict__ out) {
    __shared__ float tl[32][33];
    int b = blockIdx.z;
    int x0 = blockIdx.x * 32, y0 = blockIdx.y * 32;
    int t = threadIdx.x;
    int col = t & 31, rr = t >> 5;
    const float* src = outT + (size_t)b*NPX;
    #pragma unroll
    for (int k = 0; k < 4; k++) {
        int xr = rr + 8*k;
        tl[xr][col] = src[(size_t)(x0 + xr)*W + y0 + col];
    }
    __syncthreads();
    float* d = out + (size_t)b*NPX;
    #pragma unroll
    for (int k = 0; k < 4; k++) {
        int yr = rr + 8*k;
        d[(size_t)(y0 + yr)*W + x0 + col] = tl[col][yr];
    }
}

extern "C" void kernel_launch(void* const* d_in, const int* in_sizes, int n_in,
                              void* d_out, int out_size, void* d_ws, size_t ws_size,
                              hipStream_t stream) {
    const float* x = (const float*)d_in[0];
    float* out = (float*)d_out;
    char* w = (char*)d_ws;
    unsigned* minenc           = (unsigned*)(w + 1024);
    unsigned* maxenc           = (unsigned*)(w + 1280);
    unsigned long long* rmaxenc= (unsigned long long*)(w + 1536);
    double*  gsd               = (double*)(w + 256);
    float*   gw                = (float*)(w + 2048);                 // 6*288 floats
    unsigned* rowact           = (unsigned*)(w + 9216);              // 48*16 words
    unsigned* colBits          = (unsigned*)(w + 12288);             // 48*16 words
    float*   lap               = (float*)(w + 16384);                // 50331648 B
    char*    rb                = w + 16384 + 50331648;               // 100663296 B region
    double*  Rb                = (double*)rb;                        // fp64 R (consumed by maskTK)
    float*   Tt                = (float*)rb;                         // halo'd row-blur: 48*512*784*4 = 77070336 B
    float*   outT              = (float*)(rb + 77070336);            // 16777216 B (ends 93847552 <= 100663296)
    unsigned char* maskT       = (unsigned char*)(w + 16384 + 50331648 + 100663296); // 12582912 B

    initK<<<1, 1024, 0, stream>>>(minenc, maxenc, rmaxenc, rowact, colBits);
    gaussK<<<6, 512, 0, stream>>>(gw);
    minmaxK<<<dim3(8, 48), 256, 0, stream>>>((const float4*)x, minenc, maxenc);
    scaleK<<<1, 64, 0, stream>>>(minenc, maxenc, gsd);
    lapRK<<<dim3(16, 16, 48), 256, 0, stream>>>(x, gsd, lap, Rb, rmaxenc);
    maskTK<<<dim3(16, 16, 48), 256, 0, stream>>>(Rb, rmaxenc, maskT, rowact, colBits);

    const int rr[6] = {4, 8, 17, 34, 67, 134};
    for (int o = 0; o < 6; ++o) {
        int r = rr[o];
        int pre = (4 - (r & 3)) & 3;
        int nc8 = (pre + 2*r + 1 + 7) / 8;
        float sigma = 1.4f * (float)(1 << o);
        rowblurK2<<<dim3(64, 48), 512, 0, stream>>>(lap, Tt, gw + o*288, r, pre, nc8, rowact);
        if (o == 0)
            colblurK2<1><<<dim3(64, 16), 512, 0, stream>>>(Tt, maskT, outT, gw + o*288, r, pre, nc8, sigma, colBits);
        else
            colblurK2<0><<<dim3(64, 16), 512, 0, stream>>>(Tt, maskT, outT, gw + o*288, r, pre, nc8, sigma, colBits);
    }
    transposeK<<<dim3(16, 16, 16), 256, 0, stream>>>(outT, out);
}

// Round 12
// 718.319 us; speedup vs baseline: 1.2443x; 1.2443x over previous
//
#include <hip/hip_runtime.h>

#define W 512
#define NPX (512*512)
#define NCH 48
#define NBATCH 16

// reflect-101 index mapping into [0,511]; valid for i in [-511, 1022]
__device__ __forceinline__ int refl(int i) {
    int a = i < 0 ? -i : i;
    int b = 1022 - a;
    return a < b ? a : b;
}
__device__ __forceinline__ unsigned encf(float f) {
    unsigned u = __float_as_uint(f);
    return (u & 0x80000000u) ? ~u : (u | 0x80000000u);
}
__device__ __forceinline__ float decf(unsigned e) {
    unsigned u = (e & 0x80000000u) ? (e & 0x7FFFFFFFu) : ~e;
    return __uint_as_float(u);
}
__device__ __forceinline__ unsigned long long enc64(double d) {
    unsigned long long u = (unsigned long long)__double_as_longlong(d);
    return (u & 0x8000000000000000ULL) ? ~u : (u | 0x8000000000000000ULL);
}
__device__ __forceinline__ double dec64(unsigned long long e) {
    unsigned long long u = (e & 0x8000000000000000ULL) ? (e & 0x7FFFFFFFFFFFFFFFULL) : ~e;
    return __longlong_as_double((long long)u);
}

__global__ void initK(unsigned* minenc, unsigned* maxenc, unsigned long long* rmaxenc,
                      unsigned* rowact, unsigned* colBits) {
    int t = threadIdx.x;
    if (t < NCH) { minenc[t] = 0xFFFFFFFFu; maxenc[t] = 0u; rmaxenc[t] = 0ULL; }
    for (int i = t; i < NCH*16; i += 1024) { rowact[i] = 0u; colBits[i] = 0u; }
}

// pre-shifted weights: gw[o*288 + q] = g[q - pre] for q in [pre, pre+2r], else 0.
// pre = (4 - r%4) & 3 keeps the stage window base 16B-aligned; zero front-taps
// contribute exactly +-0 to the FMA chain -> FP-identical results.
__global__ void gaussK(float* gw) {
    int o = blockIdx.x;
    const int rr[6] = {4, 8, 17, 34, 67, 134};
    int r = rr[o];
    int pre = (4 - (r & 3)) & 3;
    float sigma = 1.4f * (float)(1 << o);
    int t = threadIdx.x;   // 512
    int n = 2*r + 1;
    float wv = 0.f;
    if (t < n) { float ft = (float)(t - r) / sigma; wv = expf(-0.5f * ft * ft); }
    __shared__ float red[512];
    red[t] = wv; __syncthreads();
    for (int s = 256; s > 0; s >>= 1) { if (t < s) red[t] += red[t + s]; __syncthreads(); }
    float sum = red[0];
    float wv2 = 0.f;
    int k = t - pre;
    if (k >= 0 && k < n) { float ft = (float)(k - r) / sigma; wv2 = expf(-0.5f * ft * ft) / sum; }
    if (t < 288) gw[o*288 + t] = wv2;
}

__global__ void minmaxK(const float4* __restrict__ x4, unsigned* minenc, unsigned* maxenc) {
    int ch = blockIdx.y, chunk = blockIdx.x, t = threadIdx.x;
    size_t base = (size_t)ch*(NPX/4) + (size_t)chunk*8192;
    float mn = 3.4e38f, mx = -3.4e38f;
    for (int i = t; i < 8192; i += 256) {
        float4 v = x4[base + i];
        mn = fminf(mn, fminf(fminf(v.x, v.y), fminf(v.z, v.w)));
        mx = fmaxf(mx, fmaxf(fmaxf(v.x, v.y), fmaxf(v.z, v.w)));
    }
    for (int o = 32; o; o >>= 1) { mn = fminf(mn, __shfl_down(mn, o)); mx = fmaxf(mx, __shfl_down(mx, o)); }
    __shared__ float smn[4], smx[4];
    if ((t & 63) == 0) { smn[t >> 6] = mn; smx[t >> 6] = mx; }
    __syncthreads();
    if (t == 0) {
        for (int i = 1; i < 4; i++) { mn = fminf(mn, smn[i]); mx = fmaxf(mx, smx[i]); }
        atomicMin(&minenc[ch], encf(mn));
        atomicMax(&maxenc[ch], encf(mx));
    }
}

__global__ void scaleK(const unsigned* minenc, const unsigned* maxenc, double* gsd) {
    int t = threadIdx.x;
    if (t >= NCH) return;
    double mn = (double)decf(minenc[t]), mx = (double)decf(maxenc[t]);
    gsd[t] = 255.0 / (mx - mn + 1e-12);
}

// Harris R (fp64 direct) + Laplacian base. 32x32 tile/block, 5.2KB LDS.
__global__ __launch_bounds__(256) void lapRK(const float* __restrict__ x, const double* __restrict__ gsd,
                      float* __restrict__ lap, double* __restrict__ Rb,
                      unsigned long long* __restrict__ rmaxenc) {
    __shared__ float in[36*36];
    int ch = blockIdx.z;
    int px0 = blockIdx.x * 32, py0 = blockIdx.y * 32;
    const float* s = x + (size_t)ch*NPX;
    int t = threadIdx.x;
    for (int i = t; i < 36*36; i += 256) {
        int yy = i / 36, xx = i - yy*36;
        in[i] = s[(size_t)refl(py0 - 2 + yy)*W + refl(px0 - 2 + xx)];
    }
    __syncthreads();
    double sd = gsd[ch], s2 = sd*sd;
    int tx = t & 31, ty0 = (t >> 5) * 4;
    int gx = px0 + tx;
    int cb = gx ? tx : 1;               // local col of window base
    double m = -1e308;
    #pragma unroll
    for (int q = 0; q < 4; q++) {
        int ly = ty0 + q;
        int gy = py0 + ly;
        int rb = gy ? ly : 1;           // local row of window base
        double w[4][4];
        #pragma unroll
        for (int j = 0; j < 4; j++) {
            const float* rp = &in[(rb + j)*36 + cb];
            w[j][0] = (double)rp[0]; w[j][1] = (double)rp[1];
            w[j][2] = (double)rp[2]; w[j][3] = (double)rp[3];
        }
        double cs1[4], cs2[4], rs[4][2];
        #pragma unroll
        for (int c2 = 0; c2 < 4; c2++) {
            cs1[c2] = w[0][c2] + 2.0*w[1][c2] + w[2][c2];
            cs2[c2] = w[1][c2] + 2.0*w[2][c2] + w[3][c2];
        }
        #pragma unroll
        for (int j = 0; j < 4; j++) {
            rs[j][0] = w[j][0] + 2.0*w[j][1] + w[j][2];
            rs[j][1] = w[j][1] + 2.0*w[j][2] + w[j][3];
        }
        double Sxx = 0, Syy = 0, Sxy = 0;
        {
            double ix, iy;
            ix = cs1[2]-cs1[0]; iy = rs[2][0]-rs[0][0]; Sxx += ix*ix; Syy += iy*iy; Sxy += ix*iy;
            ix = cs1[3]-cs1[1]; iy = rs[2][1]-rs[0][1]; Sxx += ix*ix; Syy += iy*iy; Sxy += ix*iy;
            ix = cs2[2]-cs2[0]; iy = rs[3][0]-rs[1][0]; Sxx += ix*ix; Syy += iy*iy; Sxy += ix*iy;
            ix = cs2[3]-cs2[1]; iy = rs[3][1]-rs[1][1]; Sxx += ix*ix; Syy += iy*iy; Sxy += ix*iy;
        }
        Sxx *= s2; Syy *= s2; Sxy *= s2;
        double tr = Sxx + Syy;
        double R = Sxx*Syy - Sxy*Sxy - 0.04*tr*tr;
        Rb[(size_t)ch*NPX + (size_t)gy*W + gx] = R;
        const float* c = &in[(ly+2)*36 + (tx+2)];
        double l = 2.0*((double)c[-37] + (double)c[-35] + (double)c[35] + (double)c[37]) - 8.0*(double)c[0];
        lap[(size_t)ch*NPX + (size_t)gy*W + gx] = (float)(sd * l);
        m = fmax(m, R);
    }
    for (int o = 32; o; o >>= 1) m = fmax(m, __shfl_down(m, o));
    __shared__ double sred[4];
    if ((t & 63) == 0) sred[t >> 6] = m;
    __syncthreads();
    if (t == 0) {
        for (int i = 1; i < 4; i++) m = fmax(m, sred[i]);
        atomicMax(&rmaxenc[ch], enc64(m));
    }
}

// fused threshold + 3x3 dilate; writes TRANSPOSED mask maskT[ch][x][y];
// also builds row-activity and column-activity bitmaps
__global__ __launch_bounds__(256) void maskTK(const double* __restrict__ Rb,
                                              const unsigned long long* __restrict__ rmaxenc,
                                              unsigned char* __restrict__ maskT,
                                              unsigned* __restrict__ rowact,
                                              unsigned* __restrict__ colBits) {
    __shared__ int bt[34*34];
    __shared__ unsigned char vt[32][33];
    __shared__ unsigned rw, cw;
    int ch = blockIdx.z;
    int px0 = blockIdx.x*32, py0 = blockIdx.y*32;
    double thr = 0.01 * dec64(rmaxenc[ch]);
    const double* R = Rb + (size_t)ch*NPX;
    int t = threadIdx.x;
    if (t == 0) { rw = 0u; cw = 0u; }
    for (int i = t; i < 34*34; i += 256) {
        int yy = i / 34, xx = i - yy*34;
        int gy = py0 - 1 + yy, gx = px0 - 1 + xx;
        int v = 0;
        if ((unsigned)gy < 512u && (unsigned)gx < 512u) v = (R[(size_t)gy*W + gx] > thr) ? 1 : 0;
        bt[i] = v;
    }
    __syncthreads();
    int tx = t & 31, ty0 = (t >> 5) * 4;
    int colv = 0;
    #pragma unroll
    for (int q = 0; q < 4; q++) {
        int ly = ty0 + q;
        int c = (ly+1)*34 + tx + 1;
        int v = bt[c-35] | bt[c-34] | bt[c-33] | bt[c-1] | bt[c] | bt[c+1] | bt[c+33] | bt[c+34] | bt[c+35];
        vt[tx][ly] = (unsigned char)v;
        colv |= v;
        unsigned long long bal = __ballot(v != 0);
        int lane = t & 63;
        if (lane == 0 && (unsigned)bal) atomicOr(&rw, 1u << (ty0 + q));
        if (lane == 32 && (unsigned)(bal >> 32)) atomicOr(&rw, 1u << (ty0 + q));
    }
    if (colv) atomicOr(&cw, 1u << tx);
    __syncthreads();
    int xl = t >> 3, seg = t & 7;
    uchar4 u4 = make_uchar4(vt[xl][seg*4+0], vt[xl][seg*4+1], vt[xl][seg*4+2], vt[xl][seg*4+3]);
    *(uchar4*)(maskT + (size_t)ch*NPX + (size_t)(px0 + xl)*W + py0 + seg*4) = u4;
    if (t == 0) {
        if (rw) atomicOr(&rowact[ch*16 + (py0 >> 5)], rw);
        if (cw) atomicOr(&colBits[ch*16 + blockIdx.x], cw);
    }
}

// horizontal blur, TRANSPOSED compact output Tt[ch][x][y]. 512 thr = 8 rows x
// 64 lanes; 8 outputs/lane; 8-tap chunks; SoA LDS with slot-stride 104 (bank
// form 8p+q -> max 2-way, free). Weights from GLOBAL (uniform -> SGPR).
// Output restage is thread-major (lane stride 9 -> conflict-free writes).
__global__ __launch_bounds__(512, 8) void rowblurK2(const float* __restrict__ src, float* __restrict__ Tt,
                                                    const float* __restrict__ gwo, int r, int pre, int nc8,
                                                    const unsigned* __restrict__ rowact) {
    int ch = blockIdx.y;
    int row0 = blockIdx.x * 8;
    int t = threadIdx.x;
    // early exit: no masked row in [row0-r-8, row0+7+r+8] (slop 8 covers the
    // zero-weight padded taps consumed downstream in colblur -- proof in notes)
    {
        int lo = row0 - r - 8; if (lo < 0) lo = 0;
        int hi = row0 + 15 + r; if (hi > 511) hi = 511;
        int w0 = lo >> 5, w1 = hi >> 5;
        int lane = t & 63;
        unsigned any = 0;
        if (lane <= w1 - w0) {
            int wi = w0 + lane;
            unsigned word = rowact[ch*16 + wi];
            int b0 = wi*32;
            int lo2 = lo > b0 ? lo - b0 : 0;
            int hi2 = hi < b0 + 31 ? hi - b0 : 31;
            unsigned mlo = ~0u << lo2;
            unsigned mhi = (hi2 == 31) ? ~0u : ((1u << (hi2 + 1)) - 1u);
            any = word & mlo & mhi;
        }
        if (!__any((int)(any != 0))) return;
    }
    __shared__ float ES[8*832];    // SoA (stride 104); reused as restage [512][9]
    int lr = t >> 6, xi = t & 63;
    const float* s = src + (size_t)ch*NPX + (size_t)(row0 + lr)*W;
    int rp = r + pre;                    // 0 mod 4
    int nstage = 512 + 8*nc8;
    float* ESr = ES + lr*832;
    // interior: x = 4q, element e = rp + 4q
    for (int q = xi; q < 128; q += 64) {
        float4 v = *(const float4*)(s + 4*q);
        int e0 = rp + 4*q;
        ESr[((e0+0)&7)*104 + ((e0+0)>>3)] = v.x;
        ESr[((e0+1)&7)*104 + ((e0+1)>>3)] = v.y;
        ESr[((e0+2)&7)*104 + ((e0+2)>>3)] = v.z;
        ESr[((e0+3)&7)*104 + ((e0+3)>>3)] = v.w;
    }
    // edges (reflected)
    for (int e = xi; e < rp; e += 64)
        ESr[(e&7)*104 + (e>>3)] = s[refl(e - rp)];
    for (int e = rp + 512 + xi; e < nstage; e += 64)
        ESr[(e&7)*104 + (e>>3)] = s[refl(e - rp)];
    float a[8];
    #pragma unroll
    for (int m = 0; m < 8; m++) a[m] = 0.f;
    for (int cc = 0; cc < nc8; ++cc) {
        float wv[8], f[15];
        #pragma unroll
        for (int i = 0; i < 8; i++) wv[i] = gwo[8*cc + i];   // uniform -> s_load
        #pragma unroll
        for (int j = 0; j < 15; j++) f[j] = ESr[(j & 7)*104 + (xi + cc + (j >> 3))];
        #pragma unroll
        for (int m = 0; m < 8; m++) {
            #pragma unroll
            for (int i = 0; i < 8; i++) a[m] = fmaf(wv[i], f[m + i], a[m]);
        }
    }
    __syncthreads();   // ES SoA dead; reuse as restage, thread-major
    {
        float* dst = ES + (lr*64 + xi)*9;
        #pragma unroll
        for (int m = 0; m < 8; m++) dst[m] = a[m];   // lane stride 9 -> conflict-free
    }
    __syncthreads();
    // write-out: thread t -> col c=t, rows row0..row0+7 (value for row lrr held
    // by compute thread (lrr, c>>3) slot c&7)
    {
        float o[8];
        #pragma unroll
        for (int lrr = 0; lrr < 8; lrr++)
            o[lrr] = ES[(lrr*64 + (t >> 3))*9 + (t & 7)];
        float4* d = (float4*)(Tt + (size_t)ch*NPX + (size_t)t*W + row0);
        d[0] = make_float4(o[0], o[1], o[2], o[3]);
        d[1] = make_float4(o[4], o[5], o[6], o[7]);
    }
}

// vertical blur as horizontal on compact Tt. 512 thr = 8 x-rows x 64 lanes;
// BARRIER-FREE (each wave stages and reads only its own ES row); refl staging;
// weights via SGPR; mask-gated FMA per wave; octave/channel max into outT.
template<int WRITE0>
__global__ __launch_bounds__(512, 8) void colblurK2(const float* __restrict__ Tt,
                                                    const unsigned char* __restrict__ maskT,
                                                    float* __restrict__ outT,
                                                    const float* __restrict__ gwo,
                                                    int r, int pre, int nc8, float sigma,
                                                    const unsigned* __restrict__ colBits) {
    __shared__ float ES[8*832];
    int b = blockIdx.y;
    int x0 = blockIdx.x * 8;
    int t = threadIdx.x;
    int lr = t >> 6, xi = t & 63;
    float vm[8];
    #pragma unroll
    for (int m = 0; m < 8; m++) vm[m] = 0.f;
    int anyAct = 0;
    int rp = r + pre;
    int nstage = 512 + 8*nc8;
    float* ESr = ES + lr*832;
    for (int c = 0; c < 3; ++c) {
        int ch = b*3 + c;
        unsigned cbits = (colBits[ch*16 + (x0 >> 5)] >> (x0 & 31)) & 0xFFu;
        if (!cbits) continue;            // uniform per block
        anyAct = 1;
        const float* s = Tt + (size_t)ch*NPX + (size_t)(x0 + lr)*W;
        for (int j = xi; j < nstage; j += 64)
            ESr[(j&7)*104 + (j>>3)] = s[refl(j - rp)];
        const uchar4* mp = (const uchar4*)(maskT + (size_t)ch*NPX + (size_t)(x0 + lr)*W + 8*xi);
        uchar4 m0 = mp[0], m1 = mp[1];
        unsigned mk = 0;
        mk |=  (m0.x?1u:0u)|(m0.y?2u:0u)|(m0.z?4u:0u)|(m0.w?8u:0u);
        mk |= ((m1.x?1u:0u)|(m1.y?2u:0u)|(m1.z?4u:0u)|(m1.w?8u:0u)) << 4;
        if (__any((int)(mk != 0))) {
            float a[8];
            #pragma unroll
            for (int m = 0; m < 8; m++) a[m] = 0.f;
            for (int cc = 0; cc < nc8; ++cc) {
                float wv[8], f[15];
                #pragma unroll
                for (int i = 0; i < 8; i++) wv[i] = gwo[8*cc + i];   // uniform -> s_load
                #pragma unroll
                for (int j = 0; j < 15; j++) f[j] = ESr[(j & 7)*104 + (xi + cc + (j >> 3))];
                #pragma unroll
                for (int m = 0; m < 8; m++) {
                    #pragma unroll
                    for (int i = 0; i < 8; i++) a[m] = fmaf(wv[i], f[m + i], a[m]);
                }
            }
            #pragma unroll
            for (int m = 0; m < 8; m++)
                if (mk & (1u << m)) vm[m] = fmaxf(vm[m], sigma * fabsf(a[m]));
        }
    }
    if (!WRITE0 && !anyAct) return;
    float* ob = outT + (size_t)b*NPX + (size_t)(x0 + lr)*W + 8*xi;
    #pragma unroll
    for (int q = 0; q < 2; q++) {
        float4 vv = make_float4(vm[4*q], vm[4*q+1], vm[4*q+2], vm[4*q+3]);
        if (!WRITE0) {
            float4 cur = ((const float4*)ob)[q];
            vv.x = fmaxf(vv.x, cur.x); vv.y = fmaxf(vv.y, cur.y);
            vv.z = fmaxf(vv.z, cur.z); vv.w = fmaxf(vv.w, cur.w);
        }
        ((float4*)ob)[q] = vv;
    }
}

// final transpose: out[b][y][x] = outT[b][x][y]
__global__ __launch_bounds__(256) void transposeK(const float* __restrict__ outT, float* __restrict__ out) {
    __shared__ float tl[32][33];
    int b = blockIdx.z;
    int x0 = blockIdx.x * 32, y0 = blockIdx.y * 32;
    int t = threadIdx.x;
    int col = t & 31, rr = t >> 5;
    const float* src = outT + (size_t)b*NPX;
    #pragma unroll
    for (int k = 0; k < 4; k++) {
        int xr = rr + 8*k;
        tl[xr][col] = src[(size_t)(x0 + xr)*W + y0 + col];
    }
    __syncthreads();
    float* d = out + (size_t)b*NPX;
    #pragma unroll
    for (int k = 0; k < 4; k++) {
        int yr = rr + 8*k;
        d[(size_t)(y0 + yr)*W + x0 + col] = tl[col][yr];
    }
}

extern "C" void kernel_launch(void* const* d_in, const int* in_sizes, int n_in,
                              void* d_out, int out_size, void* d_ws, size_t ws_size,
                              hipStream_t stream) {
    const float* x = (const float*)d_in[0];
    float* out = (float*)d_out;
    char* w = (char*)d_ws;
    unsigned* minenc           = (unsigned*)(w + 1024);
    unsigned* maxenc           = (unsigned*)(w + 1280);
    unsigned long long* rmaxenc= (unsigned long long*)(w + 1536);
    double*  gsd               = (double*)(w + 256);
    float*   gw                = (float*)(w + 2048);                 // 6*288 floats
    unsigned* rowact           = (unsigned*)(w + 9216);              // 48*16 words
    unsigned* colBits          = (unsigned*)(w + 12288);             // 48*16 words
    float*   lap               = (float*)(w + 16384);                // 50331648 B
    char*    rb                = w + 16384 + 50331648;               // 100663296 B region
    double*  Rb                = (double*)rb;                        // fp64 R (consumed by maskTK)
    float*   Tt                = (float*)rb;                         // compact row-blur (reuses Rb)
    float*   outT              = (float*)(rb + 50331648);            // 16777216 B
    unsigned char* maskT       = (unsigned char*)(w + 16384 + 50331648 + 100663296); // 12582912 B

    initK<<<1, 1024, 0, stream>>>(minenc, maxenc, rmaxenc, rowact, colBits);
    gaussK<<<6, 512, 0, stream>>>(gw);
    minmaxK<<<dim3(8, 48), 256, 0, stream>>>((const float4*)x, minenc, maxenc);
    scaleK<<<1, 64, 0, stream>>>(minenc, maxenc, gsd);
    lapRK<<<dim3(16, 16, 48), 256, 0, stream>>>(x, gsd, lap, Rb, rmaxenc);
    maskTK<<<dim3(16, 16, 48), 256, 0, stream>>>(Rb, rmaxenc, maskT, rowact, colBits);

    const int rr[6] = {4, 8, 17, 34, 67, 134};
    for (int o = 0; o < 6; ++o) {
        int r = rr[o];
        int pre = (4 - (r & 3)) & 3;
        int nc8 = (pre + 2*r + 1 + 7) / 8;
        float sigma = 1.4f * (float)(1 << o);
        rowblurK2<<<dim3(64, 48), 512, 0, stream>>>(lap, Tt, gw + o*288, r, pre, nc8, rowact);
        if (o == 0)
            colblurK2<1><<<dim3(64, 16), 512, 0, stream>>>(Tt, maskT, outT, gw + o*288, r, pre, nc8, sigma, colBits);
        else
            colblurK2<0><<<dim3(64, 16), 512, 0, stream>>>(Tt, maskT, outT, gw + o*288, r, pre, nc8, sigma, colBits);
    }
    transposeK<<<dim3(16, 16, 16), 256, 0, stream>>>(outT, out);
}